// Round 6
// baseline (861.172 us; speedup 1.0000x reference)
//
#include <hip/hip_runtime.h>
#include <math.h>

#define BB 16
#define CC 64
#define NN 2048
#define KK 8
#define CAND 16   // phase-1 candidates (exact top-8 subset; validated by R3)
#define TM 128    // m-tile staged in LDS
#define QW 8      // queries (waves) per block
#define NT (QW * 64)
#define NTILE (NN / TM)  // 16
#define DPL (NN / 64)    // 32 candidates owned per lane

typedef float floatx2 __attribute__((ext_vector_type(2)));
typedef unsigned long long u64;

__device__ __forceinline__ bool betterd(double d1, int i1, double d2, int i2) {
    return (d1 < d2) || (d1 == d2 && i1 < i2);
}

__global__ __launch_bounds__(NT, 2) void knn_upsample(const float* __restrict__ x,
                                                      float* __restrict__ out) {
    __shared__ float xs[CC][TM];   // 32 KB tile: [channel][m]
    __shared__ float qs[QW][CC];   // 8 query points (one per wave)

    const int tid  = threadIdx.x;
    const int w    = tid >> 6;
    const int lane = tid & 63;
    const int blk  = blockIdx.x;
    const int b    = blk >> 8;                 // 256 blocks per batch
    const int n    = ((blk & 255) << 3) + w;   // this wave's query point
    const float* xb = x + b * (CC * NN);

    qs[w][lane] = xb[lane * NN + n];
    __syncthreads();
    float q[CC];                   // plain VGPR copy (NO readfirstlane — int-only builtin risk)
#pragma unroll
    for (int c = 0; c < CC; ++c) q[c] = qs[w][c];

    // ---------------- phase 1: u64 keys (dist_bits<<32 | idx) for all 2048 points ----------------
    // fp32 distance >= 0 -> bit pattern is order-monotone; key compare == (d asc, idx asc).
    // Keys are UNIQUE -> every sort/merge comparison is tie-free -> lane-uniform results.
    u64 key[DPL];
#pragma unroll
    for (int t = 0; t < NTILE; ++t) {
        __syncthreads();
        // cooperative tile load: CC*TM/4 = 2048 float4s, 4 per thread
#pragma unroll
        for (int r = 0; r < (CC * TM / 4) / NT; ++r) {
            int v  = r * NT + tid;
            int c  = v >> 5;          // / (TM/4)
            int mv = v & 31;          // % (TM/4)
            *(float4*)(&xs[c][mv * 4]) = *(const float4*)(xb + c * NN + t * TM + mv * 4);
        }
        __syncthreads();

        // lane owns m-pair {t*128+2*lane, +1}; 4 packed accumulators for ILP
        floatx2 a0 = {0.f, 0.f}, a1 = {0.f, 0.f}, a2 = {0.f, 0.f}, a3 = {0.f, 0.f};
#pragma unroll
        for (int c = 0; c < CC; c += 4) {
            floatx2 x0 = *(const floatx2*)(&xs[c + 0][2 * lane]);
            floatx2 x1 = *(const floatx2*)(&xs[c + 1][2 * lane]);
            floatx2 x2 = *(const floatx2*)(&xs[c + 2][2 * lane]);
            floatx2 x3 = *(const floatx2*)(&xs[c + 3][2 * lane]);
            floatx2 d0 = x0 - (floatx2){q[c + 0], q[c + 0]};
            floatx2 d1 = x1 - (floatx2){q[c + 1], q[c + 1]};
            floatx2 d2 = x2 - (floatx2){q[c + 2], q[c + 2]};
            floatx2 d3 = x3 - (floatx2){q[c + 3], q[c + 3]};
            a0 = d0 * d0 + a0;  a1 = d1 * d1 + a1;
            a2 = d2 * d2 + a2;  a3 = d3 * d3 + a3;
        }
        floatx2 acc = (a0 + a1) + (a2 + a3);
        int mlo = t * TM + 2 * lane;
        key[2 * t]     = (mlo     == n) ? ~0ull
                       : (((u64)__float_as_uint(acc.x) << 32) | (unsigned)mlo);
        key[2 * t + 1] = (mlo + 1 == n) ? ~0ull
                       : (((u64)__float_as_uint(acc.y) << 32) | (unsigned)(mlo + 1));
    }

    // ---------------- per-lane bitonic sort of 32 u64 keys (ascending) ----------------
#pragma unroll
    for (int k = 2; k <= DPL; k <<= 1) {
#pragma unroll
        for (int j = k >> 1; j > 0; j >>= 1) {
#pragma unroll
            for (int i = 0; i < DPL; ++i) {
                int l = i ^ j;
                if (l > i) {
                    bool up = ((i & k) == 0);
                    bool sw = up ? (key[l] < key[i]) : (key[i] < key[l]);
                    if (sw) { u64 t2 = key[i]; key[i] = key[l]; key[l] = t2; }
                }
            }
        }
    }

    u64 k16[CAND];
#pragma unroll
    for (int j = 0; j < CAND; ++j) k16[j] = key[j];

    // ---------------- butterfly merge -> wave-global top-16 (ascending, unique keys) ----------------
#pragma unroll
    for (int off = 1; off < 64; off <<= 1) {
        u64 pk[CAND];
#pragma unroll
        for (int j = 0; j < CAND; ++j) pk[j] = __shfl_xor(k16[j], off, 64);
        u64 ck[CAND];
#pragma unroll
        for (int j = 0; j < CAND; ++j) {
            u64 a2_ = k16[j], b2_ = pk[CAND - 1 - j];
            ck[j] = (a2_ < b2_) ? a2_ : b2_;
        }
#define CMPEX(a_, b_) { if (ck[b_] < ck[a_]) { u64 t2 = ck[a_]; ck[a_] = ck[b_]; ck[b_] = t2; } }
        CMPEX(0,8) CMPEX(1,9) CMPEX(2,10) CMPEX(3,11) CMPEX(4,12) CMPEX(5,13) CMPEX(6,14) CMPEX(7,15)
        CMPEX(0,4) CMPEX(1,5) CMPEX(2,6)  CMPEX(3,7)  CMPEX(8,12) CMPEX(9,13) CMPEX(10,14) CMPEX(11,15)
        CMPEX(0,2) CMPEX(1,3) CMPEX(4,6)  CMPEX(5,7)  CMPEX(8,10) CMPEX(9,11) CMPEX(12,14) CMPEX(13,15)
        CMPEX(0,1) CMPEX(2,3) CMPEX(4,5)  CMPEX(6,7)  CMPEX(8,9)  CMPEX(10,11) CMPEX(12,13) CMPEX(14,15)
#undef CMPEX
#pragma unroll
        for (int j = 0; j < CAND; ++j) k16[j] = ck[j];
    }

    // belt-and-braces: force lane-uniform candidate list (unique keys already guarantee it)
    int i16[CAND];
#pragma unroll
    for (int j = 0; j < CAND; ++j) {
        int ii = (int)(unsigned)(k16[j] & 0xffffffffull);
        i16[j] = __shfl(ii, 0, 64);
    }

    // ---------------- phase 2: exact fp64 rescore of 16 candidates (R3-validated) ----------------
    const double qd = (double)qs[w][lane];   // lane = channel
    double e16[CAND];
#pragma unroll
    for (int j = 0; j < CAND; ++j) {
        double dt = (double)xb[lane * NN + i16[j]] - qd;
        double part = dt * dt;
#pragma unroll
        for (int off = 1; off < 64; off <<= 1)
            part += __shfl_xor(part, off, 64);
        e16[j] = part;   // identical on all lanes
    }

    // rank-count selection of exact top-8 (smallest distance, tie -> lower index)
    float ssum = 0.f;
#pragma unroll
    for (int j = 0; j < CAND; ++j) {
        int rank = 0;
#pragma unroll
        for (int k2 = 0; k2 < CAND; ++k2)
            if (betterd(e16[k2], i16[k2], e16[j], i16[j])) ++rank;
        if (rank < KK) ssum += xb[lane * NN + i16[j]];
    }
    float mean = ssum * 0.125f;

    float* ob = out + b * (CC * 2 * NN) + lane * (2 * NN);
    ob[n]      = qs[w][lane];   // first half: copy of x
    ob[NN + n] = mean;          // second half: mean of exact 8-NN features
}

extern "C" void kernel_launch(void* const* d_in, const int* in_sizes, int n_in,
                              void* d_out, int out_size, void* d_ws, size_t ws_size,
                              hipStream_t stream) {
    (void)in_sizes; (void)n_in; (void)d_ws; (void)ws_size; (void)out_size;
    const float* x = (const float*)d_in[0];
    float* out = (float*)d_out;
    knn_upsample<<<dim3(BB * NN / QW), dim3(NT), 0, stream>>>(x, out);
}

// Round 7
// 415.469 us; speedup vs baseline: 2.0728x; 2.0728x over previous
//
#include <hip/hip_runtime.h>
#include <math.h>

#define BB 16
#define CC 64
#define NN 2048
#define KK 8
#define CAND 16          // phase-1 candidates (exact top-8 subset; validated R3/R6)
#define QB 8             // queries per block (one per wave)
#define NT (QB * 64)     // 512 threads
#define MPW (NN / QB)    // 256 m-points per wave
#define DPL 32           // keys per lane in phase B

typedef float floatx2 __attribute__((ext_vector_type(2)));

__device__ __forceinline__ bool betterd(double d1, int i1, double d2, int i2) {
    return (d1 < d2) || (d1 == d2 && i1 < i2);
}

// order-preserving fp32 -> u32 flip (handles negative r): ascending uint == ascending float
__device__ __forceinline__ unsigned ordflip(float f) {
    unsigned u = __float_as_uint(f);
    return u ^ ((u & 0x80000000u) ? 0xFFFFFFFFu : 0x80000000u);
}

// xx[b,n] = sum_c x[b,c,n]^2  (fp32 proxy only — phase 2 rescores exactly)
__global__ __launch_bounds__(256) void compute_xx(const float* __restrict__ x,
                                                  float* __restrict__ xx) {
    int t = blockIdx.x * 256 + threadIdx.x;      // t in [0, B*N)
    int b = t >> 11, n = t & (NN - 1);
    const float* xb = x + b * (CC * NN) + n;
    float s = 0.f;
#pragma unroll
    for (int c = 0; c < CC; ++c) { float v = xb[c * NN]; s = fmaf(v, v, s); }
    xx[t] = s;
}

__global__ __launch_bounds__(NT, 2) void knn_upsample(const float* __restrict__ x,
                                                      const float* __restrict__ xxg,
                                                      float* __restrict__ out) {
    __shared__ unsigned keys[QB][NN];   // 64 KB: packed (r_flip_bits<<11-style) keys per query row

    const int tid  = threadIdx.x;
    const int w    = tid >> 6;                 // wave id = query id within block
    const int lane = tid & 63;
    const int blk  = blockIdx.x;
    const int b    = blk >> 8;                 // 256 blocks per batch
    const int n0   = (blk & 255) << 3;         // 8 consecutive queries per block
    const float* xb = x + b * (CC * NN);

    // ---------------- phase A: inner products, wave w covers m-slice for ALL 8 queries ----------------
    const int mbase = w * MPW + 4 * lane;      // 4 consecutive m-points per lane
    floatx2 accL[QB], accH[QB];                // acc[q] over (m0,m1) and (m2,m3)
#pragma unroll
    for (int q2 = 0; q2 < QB; ++q2) { accL[q2] = (floatx2){0.f, 0.f}; accH[q2] = (floatx2){0.f, 0.f}; }

#pragma unroll 8
    for (int c = 0; c < CC; ++c) {
        const float4 xv  = *(const float4*)(xb + c * NN + mbase);         // own 4 m-points
        const float4 qa  = *(const float4*)(xb + c * NN + n0);            // queries 0..3 (block-uniform)
        const float4 qb4 = *(const float4*)(xb + c * NN + n0 + 4);        // queries 4..7
        const floatx2 xlo = {xv.x, xv.y};
        const floatx2 xhi = {xv.z, xv.w};
        const float qv[QB] = {qa.x, qa.y, qa.z, qa.w, qb4.x, qb4.y, qb4.z, qb4.w};
#pragma unroll
        for (int q2 = 0; q2 < QB; ++q2) {
            const floatx2 qq = {qv[q2], qv[q2]};
            accL[q2] = xlo * qq + accL[q2];    // v_pk_fma_f32
            accH[q2] = xhi * qq + accH[q2];
        }
    }

    // epilogue: r = xx_m - 2*I  -> packed u32 key (idx in low 11 bits), write to LDS
    {
        const float4 xxv = *(const float4*)(xxg + b * NN + mbase);
        const float xxa[4] = {xxv.x, xxv.y, xxv.z, xxv.w};
#pragma unroll
        for (int q2 = 0; q2 < QB; ++q2) {
            const int nq = n0 + q2;
            unsigned kk[4];
#pragma unroll
            for (int p = 0; p < 4; ++p) {
                float I = (p < 2) ? ((p == 0) ? accL[q2].x : accL[q2].y)
                                  : ((p == 2) ? accH[q2].x : accH[q2].y);
                float r = fmaf(-2.f, I, xxa[p]);
                unsigned key = (ordflip(r) & 0xFFFFF800u) | (unsigned)(mbase + p);
                kk[p] = (mbase + p == nq) ? 0xFFFFFFFFu : key;   // exclude self (sorts last)
            }
            *(uint4*)(&keys[q2][mbase]) = make_uint4(kk[0], kk[1], kk[2], kk[3]);
        }
    }
    __syncthreads();

    // ---------------- phase B: wave w selects top-16 for its query n = n0 + w ----------------
    const int n = n0 + w;
    unsigned key[DPL];
#pragma unroll
    for (int s = 0; s < DPL; ++s) key[s] = keys[w][lane + 64 * s];   // stride-64: 2-way banks, free

    // per-lane bitonic sort of 32 u32 keys (ascending; keys unique -> deterministic)
#pragma unroll
    for (int k = 2; k <= DPL; k <<= 1) {
#pragma unroll
        for (int j = k >> 1; j > 0; j >>= 1) {
#pragma unroll
            for (int i = 0; i < DPL; ++i) {
                int l = i ^ j;
                if (l > i) {
                    bool up = ((i & k) == 0);
                    bool sw = up ? (key[l] < key[i]) : (key[i] < key[l]);
                    if (sw) { unsigned t2 = key[i]; key[i] = key[l]; key[l] = t2; }
                }
            }
        }
    }

    unsigned k16[CAND];
#pragma unroll
    for (int j = 0; j < CAND; ++j) k16[j] = key[j];

    // butterfly merge -> wave-global top-16 (ascending, unique keys -> lane-uniform)
#pragma unroll
    for (int off = 1; off < 64; off <<= 1) {
        unsigned pk[CAND];
#pragma unroll
        for (int j = 0; j < CAND; ++j) pk[j] = (unsigned)__shfl((int)k16[j], (lane ^ off), 64);
        unsigned ck[CAND];
#pragma unroll
        for (int j = 0; j < CAND; ++j) {
            unsigned a2_ = k16[j], b2_ = pk[CAND - 1 - j];
            ck[j] = (a2_ < b2_) ? a2_ : b2_;
        }
#define CMPEX(a_, b_) { if (ck[b_] < ck[a_]) { unsigned t2 = ck[a_]; ck[a_] = ck[b_]; ck[b_] = t2; } }
        CMPEX(0,8) CMPEX(1,9) CMPEX(2,10) CMPEX(3,11) CMPEX(4,12) CMPEX(5,13) CMPEX(6,14) CMPEX(7,15)
        CMPEX(0,4) CMPEX(1,5) CMPEX(2,6)  CMPEX(3,7)  CMPEX(8,12) CMPEX(9,13) CMPEX(10,14) CMPEX(11,15)
        CMPEX(0,2) CMPEX(1,3) CMPEX(4,6)  CMPEX(5,7)  CMPEX(8,10) CMPEX(9,11) CMPEX(12,14) CMPEX(13,15)
        CMPEX(0,1) CMPEX(2,3) CMPEX(4,5)  CMPEX(6,7)  CMPEX(8,9)  CMPEX(10,11) CMPEX(12,13) CMPEX(14,15)
#undef CMPEX
#pragma unroll
        for (int j = 0; j < CAND; ++j) k16[j] = ck[j];
    }

    // extract indices; belt-and-braces lane-0 broadcast (unique keys already guarantee uniformity)
    int i16[CAND];
#pragma unroll
    for (int j = 0; j < CAND; ++j) i16[j] = __shfl((int)(k16[j] & 0x7FFu), 0, 64);

    // ---------------- phase 2: exact fp64 rescore of 16 candidates (R3/R6-validated) ----------------
    const double qd = (double)xb[lane * NN + n];   // lane = channel
    double e16[CAND];
#pragma unroll
    for (int j = 0; j < CAND; ++j) {
        double dt = (double)xb[lane * NN + i16[j]] - qd;
        double part = dt * dt;
#pragma unroll
        for (int off = 1; off < 64; off <<= 1)
            part += __shfl_xor(part, off, 64);
        e16[j] = part;   // identical on all lanes
    }

    // rank-count selection of exact top-8 (smallest distance, tie -> lower index)
    float ssum = 0.f;
#pragma unroll
    for (int j = 0; j < CAND; ++j) {
        int rank = 0;
#pragma unroll
        for (int k2 = 0; k2 < CAND; ++k2)
            if (betterd(e16[k2], i16[k2], e16[j], i16[j])) ++rank;
        if (rank < KK) ssum += xb[lane * NN + i16[j]];
    }
    float mean = ssum * 0.125f;

    float* ob = out + b * (CC * 2 * NN) + lane * (2 * NN);
    ob[n]      = xb[lane * NN + n];   // first half: copy of x
    ob[NN + n] = mean;                // second half: mean of exact 8-NN features
}

extern "C" void kernel_launch(void* const* d_in, const int* in_sizes, int n_in,
                              void* d_out, int out_size, void* d_ws, size_t ws_size,
                              hipStream_t stream) {
    (void)in_sizes; (void)n_in; (void)ws_size; (void)out_size;
    const float* x = (const float*)d_in[0];
    float* xx = (float*)d_ws;                 // B*N floats = 128 KB scratch
    float* out = (float*)d_out;
    compute_xx<<<dim3(BB * NN / 256), dim3(256), 0, stream>>>(x, xx);
    knn_upsample<<<dim3(BB * NN / QB), dim3(NT), 0, stream>>>(x, xx, out);
}